// Round 6
// baseline (294.179 us; speedup 1.0000x reference)
//
#include <hip/hip_runtime.h>

typedef _Float16 f16;
typedef __attribute__((ext_vector_type(4))) _Float16 f16x4;
typedef __attribute__((ext_vector_type(8))) _Float16 f16x8;
typedef __attribute__((ext_vector_type(4))) float f32x4;

#define NB 2
#define NS 2048
#define NHID 2048
#define N_H 16
#define N_KV 4
#define N_HD 128

__device__ __forceinline__ void gload16(void* lds, const void* g) {
  __builtin_amdgcn_global_load_lds(
      (const __attribute__((address_space(1))) unsigned int*)g,
      (__attribute__((address_space(3))) unsigned int*)lds, 16, 0, 0);
}

// ---------------- fused f32 -> f16 convert for all 5 inputs ----------------
__global__ __launch_bounds__(256) void cvt_all(
    const float* __restrict__ hs, const float* __restrict__ Wq,
    const float* __restrict__ Wk, const float* __restrict__ Wv,
    const float* __restrict__ Wo, f16* __restrict__ Xh,
    f16* __restrict__ Wqkv, f16* __restrict__ Woh) {
  int i = blockIdx.x * 256 + threadIdx.x;  // float4 index, total 4718592
  const float* src;
  f16* dst;
  int j;
  if (i < 2097152)      { src = hs; dst = Xh;             j = i; }
  else if (i < 3145728) { src = Wq; dst = Wqkv;           j = i - 2097152; }
  else if (i < 3407872) { src = Wk; dst = Wqkv + 4194304; j = i - 3145728; }
  else if (i < 3670016) { src = Wv; dst = Wqkv + 5242880; j = i - 3407872; }
  else                  { src = Wo; dst = Woh;            j = i - 3670016; }
  const float4 v = reinterpret_cast<const float4*>(src)[j];
  f16x4 o = {(f16)v.x, (f16)v.y, (f16)v.z, (f16)v.w};
  reinterpret_cast<f16x4*>(dst)[j] = o;
}

// ---------------- QKV GEMM: BM=256 x BN=192 x BK=64, grid 256 = 1/CU ----------------
// 8 waves (2M x 4N), 2-buffer ring, stage(kt+1) before compute(kt).
// Wave-parity half order: odd waves do k-half 1 first so LDS-read and MFMA
// phases of different waves overlap instead of lockstepping after the barrier.
__global__ __launch_bounds__(512, 2) void gemm_qkv(
    const f16* __restrict__ A, const f16* __restrict__ Bm,
    f16* __restrict__ q_out, f16* __restrict__ k_out, f16* __restrict__ v_out) {
  constexpr int K = 2048;
  __shared__ f16 lds[2][28672];
  const int t = threadIdx.x;
  const int l = t & 63, w = t >> 6;
  const int g = l >> 4, l15 = l & 15;
  const int wr = w >> 2, wc = w & 3;
  const int orig = blockIdx.x;
  const int x = orig & 7, loc = orig >> 3;
  const int mb = (x & 3) * 4 + (loc & 3);
  const int nb = (x >> 2) * 8 + (loc >> 2);
  const f16* Ab = A + (size_t)(mb * 256) * K;
  const f16* Bb = Bm + (size_t)(nb * 192) * K;

  const int rA = ((t >> 5) << 3) | (t & 7);
  const int cA = (t >> 3) & 3;
  const int t2 = t & 255;
  const int rB2 = ((t2 >> 5) << 3) | (t2 & 7);
  const int cB2 = (t2 >> 3) & 3;

  auto stage = [&](int kt) {
    f16* buf = lds[kt & 1];
#pragma unroll
    for (int h = 0; h < 2; ++h) {
#pragma unroll
      for (int gi = 0; gi < 2; ++gi)
        gload16(buf + h * 8192 + gi * 4096 + w * 512,
                Ab + (size_t)(gi * 128 + rA) * K + kt * 64 + h * 32 + cA * 8);
      gload16(buf + 16384 + h * 6144 + w * 512,
              Bb + (size_t)rA * K + kt * 64 + h * 32 + cA * 8);
      if (t < 256)
        gload16(buf + 16384 + h * 6144 + 4096 + w * 512,
                Bb + (size_t)(128 + rB2) * K + kt * 64 + h * 32 + cB2 * 8);
    }
  };
  const int fragoff = ((l15 >> 3) << 8) + (g << 6) + ((l15 & 7) << 3);

  f32x4 acc[8][3] = {};

  stage(0);
  asm volatile("s_waitcnt vmcnt(0)" ::: "memory");
  __builtin_amdgcn_s_barrier();

  for (int kt = 0; kt < 32; ++kt) {
    if (kt + 1 < 32) stage(kt + 1);
    const f16* buf = lds[kt & 1];
#pragma unroll
    for (int hi = 0; hi < 2; ++hi) {
      const int h = hi ^ (w & 1);  // parity-staggered half order
      f16x8 af[8], bf[3];
#pragma unroll
      for (int mi = 0; mi < 8; ++mi)
        af[mi] = *reinterpret_cast<const f16x8*>(buf + h * 8192 + (wr * 128 + mi * 16) * 32 + fragoff);
#pragma unroll
      for (int ni = 0; ni < 3; ++ni)
        bf[ni] = *reinterpret_cast<const f16x8*>(buf + 16384 + h * 6144 + (wc * 48 + ni * 16) * 32 + fragoff);
      __builtin_amdgcn_s_setprio(1);
#pragma unroll
      for (int mi = 0; mi < 8; ++mi)
#pragma unroll
        for (int ni = 0; ni < 3; ++ni)
          acc[mi][ni] = __builtin_amdgcn_mfma_f32_16x16x32_f16(af[mi], bf[ni], acc[mi][ni], 0, 0, 0);
      __builtin_amdgcn_s_setprio(0);
    }
    if (kt + 1 < 32) asm volatile("s_waitcnt vmcnt(0)" ::: "memory");
    __builtin_amdgcn_s_barrier();
  }

#pragma unroll
  for (int mi = 0; mi < 8; ++mi) {
    int m0 = mb * 256 + wr * 128 + mi * 16 + 4 * g;
#pragma unroll
    for (int ni = 0; ni < 3; ++ni) {
      int n = nb * 192 + wc * 48 + ni * 16 + l15;
#pragma unroll
      for (int r = 0; r < 4; ++r) {
        int mm = m0 + r;
        float val = acc[mi][ni][r];
        int b = mm >> 11, s = mm & (NS - 1);
        if (n < 2048) {
          int h = n >> 7, d = n & 127;
          q_out[(((size_t)(b * N_H + h)) * NS + s) * N_HD + d] = (f16)val;
        } else if (n < 2560) {
          int n2 = n - 2048, kvh = n2 >> 7, d = n2 & 127;
          k_out[(((size_t)(b * N_KV + kvh)) * NS + s) * N_HD + d] = (f16)val;
        } else {
          int n3 = n - 2560, kvh = n3 >> 7, d = n3 & 127;
          v_out[(((size_t)(b * N_KV + kvh)) * NS + s) * N_HD + d] = (f16)val;
        }
      }
    }
  }
}

// ---------------- outproj GEMM (R4 structure, counted vmcnt ring) ----------------
template <int MREP>
__global__ __launch_bounds__(512, 2) void gemm8(
    const f16* __restrict__ A, const f16* __restrict__ Bm, const int K,
    float* __restrict__ f_out, const float* __restrict__ bias) {
  constexpr int BM = MREP * 32;
  constexpr int GA = BM / 128;
  constexpr int G = GA + 2;
  constexpr int ATILE = BM * 32;
  constexpr int BTILE = 256 * 32;
  constexpr int BUF = ATILE + BTILE;
  __shared__ f16 lds[4 * BUF];

  const int t = threadIdx.x;
  const int l = t & 63, w = t >> 6;
  const int g = l >> 4, l15 = l & 15;
  const int wr = w >> 2, wc = w & 3;
  const int orig = blockIdx.x;
  const int x = orig & 7, loc = orig >> 3;
  const int mb = (x & 3) * 8 + (loc & 7);
  const int nb = (x >> 2) * 4 + (loc >> 3);
  const int NT = K >> 5;

  const f16* Aorig = A + (size_t)(mb * BM) * K;
  const f16* Borig = Bm + (size_t)(nb * 256) * K;

  size_t offA[GA], offB[2];
#pragma unroll
  for (int gi = 0; gi < GA; ++gi) {
    int beta = gi * 8192 + t * 16;
    int r = ((beta >> 9) << 3) | ((beta >> 4) & 7);
    int c = (beta >> 7) & 3;
    offA[gi] = (size_t)r * K + c * 8;
  }
#pragma unroll
  for (int gj = 0; gj < 2; ++gj) {
    int beta = gj * 8192 + t * 16;
    int r = ((beta >> 9) << 3) | ((beta >> 4) & 7);
    int c = (beta >> 7) & 3;
    offB[gj] = (size_t)r * K + c * 8;
  }

  auto stage = [&](int kt, int gi) {
    f16* bufbase = lds + (kt & 3) * BUF;
    if (gi < GA) {
      gload16(bufbase + gi * 4096 + w * 512, Aorig + offA[gi] + kt * 32);
    } else {
      int gj = gi - GA;
      gload16(bufbase + ATILE + gj * 4096 + w * 512, Borig + offB[gj] + kt * 32);
    }
  };
  const int fragoff = ((l15 >> 3) << 8) + (g << 6) + ((l15 & 7) << 3);
  auto readA = [&](int kt, int mi) -> f16x8 {
    int R0 = wr * (MREP * 16) + mi * 16;
    return *reinterpret_cast<const f16x8*>(lds + (kt & 3) * BUF + R0 * 32 + fragoff);
  };
  auto readB = [&](int kt, int ni) -> f16x8 {
    int R0 = wc * 64 + ni * 16;
    return *reinterpret_cast<const f16x8*>(lds + (kt & 3) * BUF + ATILE + R0 * 32 + fragoff);
  };

  f32x4 acc[MREP][4] = {};

#pragma unroll
  for (int pt = 0; pt < 3; ++pt)
#pragma unroll
    for (int gi = 0; gi < G; ++gi) stage(pt, gi);
  asm volatile("s_waitcnt vmcnt(6)" ::: "memory");
  __builtin_amdgcn_s_barrier();

  for (int kt = 0; kt < NT; ++kt) {
    f16x8 af[4], bf[4];
#pragma unroll
    for (int mi = 0; mi < 4; ++mi) af[mi] = readA(kt, mi);
#pragma unroll
    for (int ni = 0; ni < 4; ++ni) bf[ni] = readB(kt, ni);
    if (kt + 3 < NT) {
      stage(kt + 3, 0);
      stage(kt + 3, 1);
      stage(kt + 3, 2);
      asm volatile("s_waitcnt vmcnt(6)" ::: "memory");
    } else if (kt + 2 < NT) {
      asm volatile("s_waitcnt vmcnt(3)" ::: "memory");
    } else if (kt + 1 < NT) {
      asm volatile("s_waitcnt vmcnt(0)" ::: "memory");
    }
    __builtin_amdgcn_s_barrier();
    asm volatile("s_waitcnt lgkmcnt(0)" ::: "memory");
    __builtin_amdgcn_s_setprio(1);
#pragma unroll
    for (int mi = 0; mi < 4; ++mi)
#pragma unroll
      for (int ni = 0; ni < 4; ++ni)
        acc[mi][ni] = __builtin_amdgcn_mfma_f32_16x16x32_f16(af[mi], bf[ni], acc[mi][ni], 0, 0, 0);
    __builtin_amdgcn_s_setprio(0);
    __builtin_amdgcn_s_barrier();
  }

#pragma unroll
  for (int mi = 0; mi < MREP; ++mi) {
    int m0 = mb * BM + wr * (MREP * 16) + mi * 16 + 4 * g;
#pragma unroll
    for (int ni = 0; ni < 4; ++ni) {
      int n = nb * 256 + wc * 64 + ni * 16 + l15;
#pragma unroll
      for (int r = 0; r < 4; ++r)
        f_out[(size_t)(m0 + r) * NHID + n] = acc[mi][ni][r] + bias[n];
    }
  }
}

// ---------------- V transpose: [B*NKV][S][HD] -> [B*NKV][HD][S] ----------------
__global__ __launch_bounds__(256) void transpose_v(const f16* __restrict__ V,
                                                   f16* __restrict__ Vt) {
  __shared__ f16 tt[64][72];
  int s0 = blockIdx.x * 64, d0 = blockIdx.y * 64, bk = blockIdx.z;
  const f16* Vp = V + (size_t)bk * NS * N_HD;
  f16* Vtp = Vt + (size_t)bk * N_HD * NS;
  int tid = threadIdx.x;
#pragma unroll
  for (int it = 0; it < 2; ++it) {
    int c = it * 256 + tid;
    int sr = c >> 3, dc = (c & 7) * 8;
    f16x8 v = *reinterpret_cast<const f16x8*>(Vp + (size_t)(s0 + sr) * N_HD + d0 + dc);
#pragma unroll
    for (int j = 0; j < 8; ++j) tt[dc + j][sr] = v[j];
  }
  __syncthreads();
#pragma unroll
  for (int it = 0; it < 2; ++it) {
    int c = it * 256 + tid;
    int dr = c >> 3, sc = (c & 7) * 8;
    f16x8 o;
#pragma unroll
    for (int j = 0; j < 8; ++j) o[j] = tt[dr][sc + j];
    *reinterpret_cast<f16x8*>(Vtp + (size_t)(d0 + dr) * NS + s0 + sc) = o;
  }
}

// ---------------- causal GQA flash attention (swapped-QK, lane-local P) ----------------
// S^T = mfma(K, Q): lane (g,l15) holds S[k=nt*16+4g+r][q=l15] -> softmax max
// needs only 2 shfl_xor; alpha/m/l are per-lane scalars. PV consumes P directly
// from registers via mfma_f32_16x16x16f16 (B-frag elems = (l>>4)*4+j = p[nt][r]).
// Output is O^T (rows d=4g+r, col q=l15) so rescale is scalar. No P-LDS at all.
__device__ __forceinline__ void stage_kv(const f16* __restrict__ Kp,
                                         const f16* __restrict__ Vp,
                                         f16* Kl, f16* Vl, int kt, int w, int l) {
#pragma unroll
  for (int it = 0; it < 4; ++it) {
    int cb = (it * 4 + w) * 64;
    int c = cb + l;
    int krow = c >> 4, pch = c & 15;
    int sch = (pch & 8) | ((pch ^ krow) & 7);
    gload16(Kl + cb * 8, Kp + (size_t)(kt * 64 + krow) * N_HD + sch * 8);
  }
#pragma unroll
  for (int it = 0; it < 4; ++it) {
    int cb = (it * 4 + w) * 64;
    int c = cb + l;
    int drow = c >> 3, pch = c & 7;
    int sch = (pch ^ drow) & 7;
    gload16(Vl + cb * 8, Vp + (size_t)drow * NS + kt * 64 + sch * 8);
  }
}

__device__ __forceinline__ void attn_step(
    const f16x8* qf, f32x4* oacc, float& mrow, float& lrow, int qg, int kbase,
    const f16* Kl, const f16* Vl, int g, int l15, bool diag) {
  // S^T: sacc[nt][r] = S[k=kbase+nt*16+4g+r][q]
  f32x4 sacc[4];
#pragma unroll
  for (int nt = 0; nt < 4; ++nt) {
    f32x4 z = {0.f, 0.f, 0.f, 0.f};
#pragma unroll
    for (int ks = 0; ks < 4; ++ks) {
      int kr = nt * 16 + l15;
      int ch = ks * 4 + g;
      int sw = (ch & 8) | ((ch ^ kr) & 7);
      f16x8 kf = *reinterpret_cast<const f16x8*>(Kl + kr * 128 + sw * 8);
      z = __builtin_amdgcn_mfma_f32_16x16x32_f16(kf, qf[ks], z, 0, 0, 0);
    }
    sacc[nt] = z;
  }

  // causal mask + in-lane max (16 vals) + 2-op cross-g reduce
  float pm[4][4];
  float m = -3.0e38f;
#pragma unroll
  for (int nt = 0; nt < 4; ++nt)
#pragma unroll
    for (int r = 0; r < 4; ++r) {
      float sv = sacc[nt][r];
      if (diag && (kbase + nt * 16 + 4 * g + r > qg)) sv = -3.0e38f;
      pm[nt][r] = sv;
      m = fmaxf(m, sv);
    }
  m = fmaxf(m, __shfl_xor(m, 16));
  m = fmaxf(m, __shfl_xor(m, 32));
  float m2 = fmaxf(mrow, m);
  float alpha = __builtin_amdgcn_exp2f(mrow - m2);
  mrow = m2;

  f16x4 p4[4];
#pragma unroll
  for (int nt = 0; nt < 4; ++nt) {
    f16x4 q4 = {(f16)__builtin_amdgcn_exp2f(pm[nt][0] - m2),
                (f16)__builtin_amdgcn_exp2f(pm[nt][1] - m2),
                (f16)__builtin_amdgcn_exp2f(pm[nt][2] - m2),
                (f16)__builtin_amdgcn_exp2f(pm[nt][3] - m2)};
    p4[nt] = q4;
  }

  // l-sum via ones-MFMA16 chain (denominator consistent with f16 P numerator)
  const f16x4 ones = {(f16)1.f, (f16)1.f, (f16)1.f, (f16)1.f};
  f32x4 lacc = {0.f, 0.f, 0.f, 0.f};
#pragma unroll
  for (int nt = 0; nt < 4; ++nt)
    lacc = __builtin_amdgcn_mfma_f32_16x16x16f16(ones, p4[nt], lacc, 0, 0, 0);
  lrow = lrow * alpha + lacc[0];

#pragma unroll
  for (int dt = 0; dt < 8; ++dt) {
    oacc[dt][0] *= alpha; oacc[dt][1] *= alpha;
    oacc[dt][2] *= alpha; oacc[dt][3] *= alpha;
  }

  // O^T += V^T x P : A = V^T[d][k-local] (b64 reads), B = p4 (in-register)
#pragma unroll
  for (int dt = 0; dt < 8; ++dt) {
    int d = dt * 16 + l15;
#pragma unroll
    for (int nt = 0; nt < 4; ++nt) {
      int ch = 2 * nt + (g >> 1);
      int sw = (ch ^ (d & 7)) & 7;
      f16x4 vf = *reinterpret_cast<const f16x4*>(Vl + d * 64 + sw * 8 + 4 * (g & 1));
      oacc[dt] = __builtin_amdgcn_mfma_f32_16x16x16f16(vf, p4[nt], oacc[dt], 0, 0, 0);
    }
  }
}

__global__ __launch_bounds__(256, 2) void attn_kernel(
    const f16* __restrict__ Q, const f16* __restrict__ K,
    const f16* __restrict__ Vt, f16* __restrict__ O) {
  __shared__ f16 Klds[2][64 * 128];
  __shared__ f16 Vlds[2][128 * 64];
  const int t = threadIdx.x, l = t & 63, w = t >> 6;
  const int g = l >> 4, l15 = l & 15;
  // XCD swizzle: XCD x owns one (b,kvh) group so K/V stays L2-resident
  const int orig = blockIdx.x;               // 0..511
  const int x = orig & 7, loc = orig >> 3;   // loc 0..63
  const int b = x >> 2, kvh = x & 3;
  const int h = kvh * 4 + (loc & 3);
  const int pi = loc >> 2;                   // 0..15
  const int qtA = pi, qtB = 31 - pi;
  const f16* Qp = Q + ((size_t)(b * N_H + h)) * NS * N_HD;
  const f16* Kp = K + ((size_t)(b * N_KV + kvh)) * NS * N_HD;
  const f16* Vp = Vt + ((size_t)(b * N_KV + kvh)) * N_HD * NS;

  const f16 l2e = (f16)1.44269504f;
  f16x8 qfA[4], qfB[4];
  const int qgA = qtA * 64 + w * 16 + l15;
  const int qgB = qtB * 64 + w * 16 + l15;
#pragma unroll
  for (int ks = 0; ks < 4; ++ks) {
    qfA[ks] = *reinterpret_cast<const f16x8*>(Qp + (size_t)qgA * N_HD + ks * 32 + g * 8);
    qfB[ks] = *reinterpret_cast<const f16x8*>(Qp + (size_t)qgB * N_HD + ks * 32 + g * 8);
#pragma unroll
    for (int j = 0; j < 8; ++j) { qfA[ks][j] *= l2e; qfB[ks][j] *= l2e; }
  }

  f32x4 oA[8] = {}, oB[8] = {};
  float mA = -3.0e38f, lA = 0.f, mB = -3.0e38f, lB = 0.f;

  const int nkt = qtB + 1;
  stage_kv(Kp, Vp, Klds[0], Vlds[0], 0, w, l);
  asm volatile("s_waitcnt vmcnt(0)" ::: "memory");
  __syncthreads();
  int cur = 0;
  for (int kt = 0; kt < nkt; ++kt) {
    if (kt + 1 < nkt)
      stage_kv(Kp, Vp, Klds[cur ^ 1], Vlds[cur ^ 1], kt + 1, w, l);
    attn_step(qfB, oB, mB, lB, qgB, kt * 64, Klds[cur], Vlds[cur], g, l15, kt == qtB);
    if (kt <= qtA)
      attn_step(qfA, oA, mA, lA, qgA, kt * 64, Klds[cur], Vlds[cur], g, l15, kt == qtA);
    asm volatile("s_waitcnt vmcnt(0)" ::: "memory");
    __syncthreads();
    cur ^= 1;
  }

  // O^T -> normalize + write: lane (g,l15) holds O[q=l15-row][d=dt*16+4g+r]
  float invB = 1.0f / lB;
  f16* orowB = O + (size_t)(b * NS + qgB) * NHID + h * N_HD;
#pragma unroll
  for (int dt = 0; dt < 8; ++dt) {
    f16x4 o4 = {(f16)(oB[dt][0] * invB), (f16)(oB[dt][1] * invB),
                (f16)(oB[dt][2] * invB), (f16)(oB[dt][3] * invB)};
    *reinterpret_cast<f16x4*>(orowB + dt * 16 + 4 * g) = o4;
  }
  float invA = 1.0f / lA;
  f16* orowA = O + (size_t)(b * NS + qgA) * NHID + h * N_HD;
#pragma unroll
  for (int dt = 0; dt < 8; ++dt) {
    f16x4 o4 = {(f16)(oA[dt][0] * invA), (f16)(oA[dt][1] * invA),
                (f16)(oA[dt][2] * invA), (f16)(oA[dt][3] * invA)};
    *reinterpret_cast<f16x4*>(orowA + dt * 16 + 4 * g) = o4;
  }
}

extern "C" void kernel_launch(void* const* d_in, const int* in_sizes, int n_in,
                              void* d_out, int out_size, void* d_ws, size_t ws_size,
                              hipStream_t stream) {
  const float* hs = (const float*)d_in[0];
  const float* Wq = (const float*)d_in[1];
  const float* Wk = (const float*)d_in[2];
  const float* Wv = (const float*)d_in[3];
  const float* Wo = (const float*)d_in[4];
  const float* bo = (const float*)d_in[5];
  float* out = (float*)d_out;

  char* ws = (char*)d_ws;
  f16* Xh   = (f16*)(ws);
  f16* Wqkv = (f16*)(ws + 16777216);
  f16* Woh  = (f16*)(ws + 29360128);
  f16* Qb   = (f16*)(ws + 37748736);
  f16* Kb   = (f16*)(ws + 54525952);
  f16* Vb   = (f16*)(ws + 58720256);
  f16* Vtb  = (f16*)(ws + 62914560);
  f16* Ob   = Xh;  // X dead after QKV GEMM; reuse for attention output

  cvt_all<<<18432, 256, 0, stream>>>(hs, Wq, Wk, Wv, Wo, Xh, Wqkv, Woh);
  gemm_qkv<<<256, 512, 0, stream>>>(Xh, Wqkv, Qb, Kb, Vb);
  transpose_v<<<dim3(32, 2, 8), 256, 0, stream>>>(Vb, Vtb);
  attn_kernel<<<512, 256, 0, stream>>>(Qb, Kb, Vtb, Ob);
  gemm8<4><<<256, 512, 0, stream>>>(Ob, Woh, 2048, out, bo);
}

// Round 7
// 212.839 us; speedup vs baseline: 1.3822x; 1.3822x over previous
//
#include <hip/hip_runtime.h>

typedef _Float16 f16;
typedef __attribute__((ext_vector_type(4))) _Float16 f16x4;
typedef __attribute__((ext_vector_type(8))) _Float16 f16x8;
typedef __attribute__((ext_vector_type(4))) float f32x4;

#define NB 2
#define NS 2048
#define NHID 2048
#define N_H 16
#define N_KV 4
#define N_HD 128

__device__ __forceinline__ void gload16(void* lds, const void* g) {
  __builtin_amdgcn_global_load_lds(
      (const __attribute__((address_space(1))) unsigned int*)g,
      (__attribute__((address_space(3))) unsigned int*)lds, 16, 0, 0);
}

// ---------------- fused f32 -> f16 convert for all 5 inputs ----------------
__global__ __launch_bounds__(256) void cvt_all(
    const float* __restrict__ hs, const float* __restrict__ Wq,
    const float* __restrict__ Wk, const float* __restrict__ Wv,
    const float* __restrict__ Wo, f16* __restrict__ Xh,
    f16* __restrict__ Wqkv, f16* __restrict__ Woh) {
  int i = blockIdx.x * 256 + threadIdx.x;  // float4 index, total 4718592
  const float* src;
  f16* dst;
  int j;
  if (i < 2097152)      { src = hs; dst = Xh;             j = i; }
  else if (i < 3145728) { src = Wq; dst = Wqkv;           j = i - 2097152; }
  else if (i < 3407872) { src = Wk; dst = Wqkv + 4194304; j = i - 3145728; }
  else if (i < 3670016) { src = Wv; dst = Wqkv + 5242880; j = i - 3407872; }
  else                  { src = Wo; dst = Woh;            j = i - 3670016; }
  const float4 v = reinterpret_cast<const float4*>(src)[j];
  f16x4 o = {(f16)v.x, (f16)v.y, (f16)v.z, (f16)v.w};
  reinterpret_cast<f16x4*>(dst)[j] = o;
}

// ---------------- QKV GEMM: 8-phase m201-style, 256x256 x BK=64 ----------------
// 8 waves (2M x 4N; wave = 128x64). 2 LDS buffers (64KB each). 4 phases per
// K-tile: phase q reads A-frag rows 2q,2q+1 (+ all B at q=0), stages ONE
// 16KB half-tile, then {barrier, lgkmcnt(0), 16 MFMA, barrier}. Staging leads
// compute by 6 half-tiles, B-halves first (B of a tile is last read at its
// phase 0, A at phase 3 -> every LDS overwrite lands after the 2-tiles-ago
// reads completed). Counted vmcnt(4) per tile boundary; vmcnt(0) only at the
// last tile. Granule-permuted LDS (128x32 granules, R5-verified mapping).
__global__ __launch_bounds__(512, 2) void gemm_qkv(
    const f16* __restrict__ A, const f16* __restrict__ Bm,
    f16* __restrict__ q_out, f16* __restrict__ k_out, f16* __restrict__ v_out) {
  constexpr int K = 2048;
  constexpr int NT = 32;                 // K tiles of 64
  __shared__ f16 lds[2][32768];          // per buf: A[ks*8192+row*32] 16K f16 | B same
  const int t = threadIdx.x;
  const int l = t & 63, w = t >> 6;
  const int g = l >> 4, l15 = l & 15;
  const int wr = w >> 2, wc = w & 3;     // 2 x 4 wave grid
  // XCD-rectangle swizzle over 16mb x 12nb (grid 192)
  const int orig = blockIdx.x;
  const int x = orig & 7, loc = orig >> 3;  // loc 0..23
  const int mb = (x & 3) * 4 + (loc & 3);
  const int nb = (x >> 2) * 6 + (loc >> 2);
  const f16* Ab = A + (size_t)(mb * 256) * K;
  const f16* Bb = Bm + (size_t)(nb * 256) * K;

  // within-granule thread mapping (granule = 128 rows x 32 cols, 8KB)
  const int rr = ((t >> 5) << 3) | (t & 7);  // row 0..127
  const int cc = (t >> 3) & 3;               // 8-f16 col chunk

  auto stageA = [&](int tile, int h) {   // A col-half h: granules gi=0,1
    f16* dstbase = lds[tile & 1] + h * 8192;
    size_t so = (size_t)rr * K + tile * 64 + h * 32 + cc * 8;
#pragma unroll
    for (int gi = 0; gi < 2; ++gi)
      gload16(dstbase + gi * 4096 + w * 512, Ab + so + (size_t)(gi * 128) * K);
  };
  auto stageB = [&](int tile, int h) {
    f16* dstbase = lds[tile & 1] + 16384 + h * 8192;
    size_t so = (size_t)rr * K + tile * 64 + h * 32 + cc * 8;
#pragma unroll
    for (int gi = 0; gi < 2; ++gi)
      gload16(dstbase + gi * 4096 + w * 512, Bb + so + (size_t)(gi * 128) * K);
  };
  auto stage_n = [&](int n) {            // n = 4*tile + j, j: {B0,B1,A0,A1}
    if (n >= 4 * NT) return;
    int tile = n >> 2, j = n & 3;
    if (j < 2) stageB(tile, j);
    else       stageA(tile, j - 2);
  };

  const int fragoff = ((l15 >> 3) << 8) + (g << 6) + ((l15 & 7) << 3);
  auto readA = [&](int tile, int mr, int ks) -> f16x8 {
    return *reinterpret_cast<const f16x8*>(
        lds[tile & 1] + ks * 8192 + (wr * 128 + mr * 16) * 32 + fragoff);
  };
  auto readB = [&](int tile, int ni, int ks) -> f16x8 {
    return *reinterpret_cast<const f16x8*>(
        lds[tile & 1] + 16384 + ks * 8192 + (wc * 64 + ni * 16) * 32 + fragoff);
  };

  f32x4 acc[8][4] = {};

  // prologue: tile0 {B0,B1,A0,A1} + tile1 {B0,B1}; wait so tile0 is complete
#pragma unroll
  for (int n = 0; n < 6; ++n) stage_n(n);
  asm volatile("s_waitcnt vmcnt(4)" ::: "memory");
  __builtin_amdgcn_s_barrier();

  f16x8 bf[4][2];
  for (int T = 0; T < NT; ++T) {
#pragma unroll
    for (int q = 0; q < 4; ++q) {
      if (q == 0 && T > 0) {
        if (T == NT - 1) asm volatile("s_waitcnt vmcnt(0)" ::: "memory");
        else             asm volatile("s_waitcnt vmcnt(4)" ::: "memory");
      }
      f16x8 af[2][2];
#pragma unroll
      for (int i = 0; i < 2; ++i)
#pragma unroll
        for (int ks = 0; ks < 2; ++ks)
          af[i][ks] = readA(T, 2 * q + i, ks);
      if (q == 0) {
#pragma unroll
        for (int ni = 0; ni < 4; ++ni)
#pragma unroll
          for (int ks = 0; ks < 2; ++ks)
            bf[ni][ks] = readB(T, ni, ks);
      }
      stage_n(T * 4 + q + 6);
      if (q == 0) asm volatile("s_waitcnt lgkmcnt(8)" ::: "memory");
      __builtin_amdgcn_s_barrier();
      asm volatile("s_waitcnt lgkmcnt(0)" ::: "memory");
      __builtin_amdgcn_sched_barrier(0);
      __builtin_amdgcn_s_setprio(1);
#pragma unroll
      for (int i = 0; i < 2; ++i)
#pragma unroll
        for (int ni = 0; ni < 4; ++ni)
#pragma unroll
          for (int ks = 0; ks < 2; ++ks)
            acc[2 * q + i][ni] = __builtin_amdgcn_mfma_f32_16x16x32_f16(
                af[i][ks], bf[ni][ks], acc[2 * q + i][ni], 0, 0, 0);
      __builtin_amdgcn_s_setprio(0);
      __builtin_amdgcn_s_barrier();
    }
  }

  // scatter epilogue: D[row=4g+r][col=l15] per fragment
#pragma unroll
  for (int mi = 0; mi < 8; ++mi) {
    int m0 = mb * 256 + wr * 128 + mi * 16 + 4 * g;
#pragma unroll
    for (int ni = 0; ni < 4; ++ni) {
      int n = nb * 256 + wc * 64 + ni * 16 + l15;
#pragma unroll
      for (int r = 0; r < 4; ++r) {
        int mm = m0 + r;
        float val = acc[mi][ni][r];
        int b = mm >> 11, s = mm & (NS - 1);
        if (n < 2048) {
          int h = n >> 7, d = n & 127;
          q_out[(((size_t)(b * N_H + h)) * NS + s) * N_HD + d] = (f16)val;
        } else if (n < 2560) {
          int n2 = n - 2048, kvh = n2 >> 7, d = n2 & 127;
          k_out[(((size_t)(b * N_KV + kvh)) * NS + s) * N_HD + d] = (f16)val;
        } else {
          int n3 = n - 2560, kvh = n3 >> 7, d = n3 & 127;
          v_out[(((size_t)(b * N_KV + kvh)) * NS + s) * N_HD + d] = (f16)val;
        }
      }
    }
  }
}

// ---------------- outproj GEMM (R5 structure, counted vmcnt ring) ----------------
template <int MREP>
__global__ __launch_bounds__(512, 2) void gemm8(
    const f16* __restrict__ A, const f16* __restrict__ Bm, const int K,
    float* __restrict__ f_out, const float* __restrict__ bias) {
  constexpr int BM = MREP * 32;
  constexpr int GA = BM / 128;
  constexpr int G = GA + 2;
  constexpr int ATILE = BM * 32;
  constexpr int BTILE = 256 * 32;
  constexpr int BUF = ATILE + BTILE;
  __shared__ f16 lds[4 * BUF];

  const int t = threadIdx.x;
  const int l = t & 63, w = t >> 6;
  const int g = l >> 4, l15 = l & 15;
  const int wr = w >> 2, wc = w & 3;
  const int orig = blockIdx.x;
  const int x = orig & 7, loc = orig >> 3;
  const int mb = (x & 3) * 8 + (loc & 7);
  const int nb = (x >> 2) * 4 + (loc >> 3);
  const int NT = K >> 5;

  const f16* Aorig = A + (size_t)(mb * BM) * K;
  const f16* Borig = Bm + (size_t)(nb * 256) * K;

  size_t offA[GA], offB[2];
#pragma unroll
  for (int gi = 0; gi < GA; ++gi) {
    int beta = gi * 8192 + t * 16;
    int r = ((beta >> 9) << 3) | ((beta >> 4) & 7);
    int c = (beta >> 7) & 3;
    offA[gi] = (size_t)r * K + c * 8;
  }
#pragma unroll
  for (int gj = 0; gj < 2; ++gj) {
    int beta = gj * 8192 + t * 16;
    int r = ((beta >> 9) << 3) | ((beta >> 4) & 7);
    int c = (beta >> 7) & 3;
    offB[gj] = (size_t)r * K + c * 8;
  }

  auto stage = [&](int kt, int gi) {
    f16* bufbase = lds + (kt & 3) * BUF;
    if (gi < GA) {
      gload16(bufbase + gi * 4096 + w * 512, Aorig + offA[gi] + kt * 32);
    } else {
      int gj = gi - GA;
      gload16(bufbase + ATILE + gj * 4096 + w * 512, Borig + offB[gj] + kt * 32);
    }
  };
  const int fragoff = ((l15 >> 3) << 8) + (g << 6) + ((l15 & 7) << 3);
  auto readA = [&](int kt, int mi) -> f16x8 {
    int R0 = wr * (MREP * 16) + mi * 16;
    return *reinterpret_cast<const f16x8*>(lds + (kt & 3) * BUF + R0 * 32 + fragoff);
  };
  auto readB = [&](int kt, int ni) -> f16x8 {
    int R0 = wc * 64 + ni * 16;
    return *reinterpret_cast<const f16x8*>(lds + (kt & 3) * BUF + ATILE + R0 * 32 + fragoff);
  };

  f32x4 acc[MREP][4] = {};

#pragma unroll
  for (int pt = 0; pt < 3; ++pt)
#pragma unroll
    for (int gi = 0; gi < G; ++gi) stage(pt, gi);
  asm volatile("s_waitcnt vmcnt(6)" ::: "memory");
  __builtin_amdgcn_s_barrier();

  for (int kt = 0; kt < NT; ++kt) {
    f16x8 af[4], bf[4];
#pragma unroll
    for (int mi = 0; mi < 4; ++mi) af[mi] = readA(kt, mi);
#pragma unroll
    for (int ni = 0; ni < 4; ++ni) bf[ni] = readB(kt, ni);
    if (kt + 3 < NT) {
      stage(kt + 3, 0);
      stage(kt + 3, 1);
      stage(kt + 3, 2);
      asm volatile("s_waitcnt vmcnt(6)" ::: "memory");
    } else if (kt + 2 < NT) {
      asm volatile("s_waitcnt vmcnt(3)" ::: "memory");
    } else if (kt + 1 < NT) {
      asm volatile("s_waitcnt vmcnt(0)" ::: "memory");
    }
    __builtin_amdgcn_s_barrier();
    asm volatile("s_waitcnt lgkmcnt(0)" ::: "memory");
    __builtin_amdgcn_s_setprio(1);
#pragma unroll
    for (int mi = 0; mi < 4; ++mi)
#pragma unroll
      for (int ni = 0; ni < 4; ++ni)
        acc[mi][ni] = __builtin_amdgcn_mfma_f32_16x16x32_f16(af[mi], bf[ni], acc[mi][ni], 0, 0, 0);
    __builtin_amdgcn_s_setprio(0);
    __builtin_amdgcn_s_barrier();
  }

#pragma unroll
  for (int mi = 0; mi < MREP; ++mi) {
    int m0 = mb * BM + wr * (MREP * 16) + mi * 16 + 4 * g;
#pragma unroll
    for (int ni = 0; ni < 4; ++ni) {
      int n = nb * 256 + wc * 64 + ni * 16 + l15;
#pragma unroll
      for (int r = 0; r < 4; ++r)
        f_out[(size_t)(m0 + r) * NHID + n] = acc[mi][ni][r] + bias[n];
    }
  }
}

// ---------------- V transpose: [B*NKV][S][HD] -> [B*NKV][HD][S] ----------------
__global__ __launch_bounds__(256) void transpose_v(const f16* __restrict__ V,
                                                   f16* __restrict__ Vt) {
  __shared__ f16 tt[64][72];
  int s0 = blockIdx.x * 64, d0 = blockIdx.y * 64, bk = blockIdx.z;
  const f16* Vp = V + (size_t)bk * NS * N_HD;
  f16* Vtp = Vt + (size_t)bk * N_HD * NS;
  int tid = threadIdx.x;
#pragma unroll
  for (int it = 0; it < 2; ++it) {
    int c = it * 256 + tid;
    int sr = c >> 3, dc = (c & 7) * 8;
    f16x8 v = *reinterpret_cast<const f16x8*>(Vp + (size_t)(s0 + sr) * N_HD + d0 + dc);
#pragma unroll
    for (int j = 0; j < 8; ++j) tt[dc + j][sr] = v[j];
  }
  __syncthreads();
#pragma unroll
  for (int it = 0; it < 2; ++it) {
    int c = it * 256 + tid;
    int dr = c >> 3, sc = (c & 7) * 8;
    f16x8 o;
#pragma unroll
    for (int j = 0; j < 8; ++j) o[j] = tt[dr][sc + j];
    *reinterpret_cast<f16x8*>(Vtp + (size_t)(d0 + dr) * NS + s0 + sc) = o;
  }
}

// ---------------- causal GQA flash attention (R5 structure, known-good) ----------------
__device__ __forceinline__ void stage_kv(const f16* __restrict__ Kp,
                                         const f16* __restrict__ Vp,
                                         f16* Kl, f16* Vl, int kt, int w, int l) {
#pragma unroll
  for (int it = 0; it < 4; ++it) {
    int cb = (it * 4 + w) * 64;
    int c = cb + l;
    int krow = c >> 4, pch = c & 15;
    int sch = (pch & 8) | ((pch ^ krow) & 7);
    gload16(Kl + cb * 8, Kp + (size_t)(kt * 64 + krow) * N_HD + sch * 8);
  }
#pragma unroll
  for (int it = 0; it < 4; ++it) {
    int cb = (it * 4 + w) * 64;
    int c = cb + l;
    int drow = c >> 3, pch = c & 7;
    int sch = (pch ^ drow) & 7;
    gload16(Vl + cb * 8, Vp + (size_t)drow * NS + kt * 64 + sch * 8);
  }
}

__device__ __forceinline__ void attn_step(
    const f16x8* qf, f32x4* oacc, float* mrow, float* lrow, int q0, int kt,
    const f16* Kl, const f16* Vl, f16* Pw, int g, int l15, bool diag) {
  // S = Q K^T (Q pre-scaled by log2e): acc D[q=4g+r][kpos=l15+16nt]
  f32x4 sacc[4];
#pragma unroll
  for (int nt = 0; nt < 4; ++nt) {
    f32x4 z = {0.f, 0.f, 0.f, 0.f};
#pragma unroll
    for (int ks = 0; ks < 4; ++ks) {
      int kr = nt * 16 + l15;
      int ch = ks * 4 + g;
      int sw = (ch & 8) | ((ch ^ kr) & 7);
      f16x8 kf = *reinterpret_cast<const f16x8*>(Kl + kr * 128 + sw * 8);
      z = __builtin_amdgcn_mfma_f32_16x16x32_f16(qf[ks], kf, z, 0, 0, 0);
    }
    sacc[nt] = z;
  }

  // causal mask + wave-parallel max; exp2; scale old state
  float p[4][4];
#pragma unroll
  for (int r = 0; r < 4; ++r) {
    int qg = q0 + r;
    float m = -3.0e38f;
#pragma unroll
    for (int nt = 0; nt < 4; ++nt) {
      float sv = sacc[nt][r];
      if (diag) {
        int kg = kt * 64 + nt * 16 + l15;
        if (kg > qg) sv = -3.0e38f;
      }
      p[nt][r] = sv;
      m = fmaxf(m, sv);
    }
#pragma unroll
    for (int off = 8; off >= 1; off >>= 1) m = fmaxf(m, __shfl_xor(m, off));
    float m2 = fmaxf(mrow[r], m);
    float alpha = __builtin_amdgcn_exp2f(mrow[r] - m2);
    mrow[r] = m2;
    lrow[r] *= alpha;
#pragma unroll
    for (int nt = 0; nt < 4; ++nt)
      p[nt][r] = __builtin_amdgcn_exp2f(p[nt][r] - m2);
#pragma unroll
    for (int dt = 0; dt < 8; ++dt) oacc[dt][r] *= alpha;
  }

  // P -> per-wave LDS (swizzled), then read back as A-op fragments
#pragma unroll
  for (int nt = 0; nt < 4; ++nt)
#pragma unroll
    for (int r = 0; r < 4; ++r) {
      int ql = 4 * g + r;
      int kp = nt * 16 + l15;
      int ch = kp >> 3;
      int idx = ql * 64 + (ch ^ (ql & 7)) * 8 + (kp & 7);
      Pw[idx] = (f16)p[nt][r];
    }
  asm volatile("s_waitcnt lgkmcnt(0)" ::: "memory");
  __builtin_amdgcn_sched_barrier(0);

  f16x8 pa[2];
#pragma unroll
  for (int ks2 = 0; ks2 < 2; ++ks2) {
    int ch = ks2 * 4 + g;
    pa[ks2] = *reinterpret_cast<const f16x8*>(&Pw[l15 * 64 + (ch ^ (l15 & 7)) * 8]);
  }
  // row-sum via ones-MFMA (all lanes get Sum_k P[row,k] in lacc[r])
  const f16x8 ones = {(f16)1.f, (f16)1.f, (f16)1.f, (f16)1.f,
                      (f16)1.f, (f16)1.f, (f16)1.f, (f16)1.f};
  f32x4 lacc = {0.f, 0.f, 0.f, 0.f};
#pragma unroll
  for (int ks2 = 0; ks2 < 2; ++ks2)
    lacc = __builtin_amdgcn_mfma_f32_16x16x32_f16(pa[ks2], ones, lacc, 0, 0, 0);
  // O += P V : B-op = V[k][d] from Vl[d][k]
#pragma unroll
  for (int dt = 0; dt < 8; ++dt)
#pragma unroll
    for (int ks2 = 0; ks2 < 2; ++ks2) {
      int d = dt * 16 + l15;
      int ch = ks2 * 4 + g;
      f16x8 vf = *reinterpret_cast<const f16x8*>(Vl + d * 64 + (ch ^ (d & 7)) * 8);
      oacc[dt] = __builtin_amdgcn_mfma_f32_16x16x32_f16(pa[ks2], vf, oacc[dt], 0, 0, 0);
    }
#pragma unroll
  for (int r = 0; r < 4; ++r) lrow[r] += lacc[r];
}

__global__ __launch_bounds__(256, 2) void attn_kernel(
    const f16* __restrict__ Q, const f16* __restrict__ K,
    const f16* __restrict__ Vt, f16* __restrict__ O) {
  __shared__ f16 Klds[2][64 * 128];
  __shared__ f16 Vlds[2][128 * 64];
  __shared__ f16 Plds[4][16 * 64];
  const int t = threadIdx.x, l = t & 63, w = t >> 6;
  const int g = l >> 4, l15 = l & 15;
  // XCD swizzle: XCD x owns (b,kvh) group so K/V stays L2-resident
  const int orig = blockIdx.x;               // 0..511
  const int x = orig & 7, loc = orig >> 3;   // loc 0..63
  const int b = x >> 2, kvh = x & 3;
  const int h = kvh * 4 + (loc & 3);
  const int pi = loc >> 2;                   // 0..15
  const int qtA = pi, qtB = 31 - pi;
  const f16* Qp = Q + ((size_t)(b * N_H + h)) * NS * N_HD;
  const f16* Kp = K + ((size_t)(b * N_KV + kvh)) * NS * N_HD;
  const f16* Vp = Vt + ((size_t)(b * N_KV + kvh)) * N_HD * NS;

  const f16 l2e = (f16)1.44269504f;
  f16x8 qfA[4], qfB[4];
  const int qrA = qtA * 64 + w * 16 + l15;
  const int qrB = qtB * 64 + w * 16 + l15;
#pragma unroll
  for (int ks = 0; ks < 4; ++ks) {
    qfA[ks] = *reinterpret_cast<const f16x8*>(Qp + (size_t)qrA * N_HD + ks * 32 + g * 8);
    qfB[ks] = *reinterpret_cast<const f16x8*>(Qp + (size_t)qrB * N_HD + ks * 32 + g * 8);
#pragma unroll
    for (int j = 0; j < 8; ++j) { qfA[ks][j] *= l2e; qfB[ks][j] *= l2e; }
  }

  f32x4 oA[8] = {}, oB[8] = {};
  float mA[4], lAr[4], mB[4], lBr[4];
#pragma unroll
  for (int r = 0; r < 4; ++r) {
    mA[r] = -3.0e38f; lAr[r] = 0.f;
    mB[r] = -3.0e38f; lBr[r] = 0.f;
  }
  const int q0A = qtA * 64 + w * 16 + 4 * g;
  const int q0B = qtB * 64 + w * 16 + 4 * g;

  const int nkt = qtB + 1;
  stage_kv(Kp, Vp, Klds[0], Vlds[0], 0, w, l);
  asm volatile("s_waitcnt vmcnt(0)" ::: "memory");
  __syncthreads();
  int cur = 0;
  for (int kt = 0; kt < nkt; ++kt) {
    if (kt + 1 < nkt)
      stage_kv(Kp, Vp, Klds[cur ^ 1], Vlds[cur ^ 1], kt + 1, w, l);
    attn_step(qfB, oB, mB, lBr, q0B, kt, Klds[cur], Vlds[cur], Plds[w], g, l15, kt == qtB);
    if (kt <= qtA)
      attn_step(qfA, oA, mA, lAr, q0A, kt, Klds[cur], Vlds[cur], Plds[w], g, l15, kt == qtA);
    asm volatile("s_waitcnt vmcnt(0)" ::: "memory");
    __syncthreads();
    cur ^= 1;
  }

  // normalize + write attn_out [B*S][NH*HD] fp16
#pragma unroll
  for (int r = 0; r < 4; ++r) {
    float invB = 1.0f / lBr[r];
    f16* orowB = O + (size_t)(b * NS + q0B + r) * NHID + h * N_HD;
#pragma unroll
    for (int dt = 0; dt < 8; ++dt) orowB[dt * 16 + l15] = (f16)(oB[dt][r] * invB);
    float invA = 1.0f / lAr[r];
    f16* orowA = O + (size_t)(b * NS + q0A + r) * NHID + h * N_HD;
#pragma unroll
    for (int dt = 0; dt < 8; ++dt) orowA[dt * 16 + l15] = (f16)(oA[dt][r] * invA);
  }
}

extern "C" void kernel_launch(void* const* d_in, const int* in_sizes, int n_in,
                              void* d_out, int out_size, void* d_ws, size_t ws_size,
                              hipStream_t stream) {
  const float* hs = (const float*)d_in[0];
  const float* Wq = (const float*)d_in[1];
  const float* Wk = (const float*)d_in[2];
  const float* Wv = (const float*)d_in[3];
  const float* Wo = (const float*)d_in[4];
  const float* bo = (const float*)d_in[5];
  float* out = (float*)d_out;

  char* ws = (char*)d_ws;
  f16* Xh   = (f16*)(ws);
  f16* Wqkv = (f16*)(ws + 16777216);
  f16* Woh  = (f16*)(ws + 29360128);
  f16* Qb   = (f16*)(ws + 37748736);
  f16* Kb   = (f16*)(ws + 54525952);
  f16* Vb   = (f16*)(ws + 58720256);
  f16* Vtb  = (f16*)(ws + 62914560);
  f16* Ob   = Xh;  // X dead after QKV GEMM; reuse for attention output

  cvt_all<<<18432, 256, 0, stream>>>(hs, Wq, Wk, Wv, Wo, Xh, Wqkv, Woh);
  gemm_qkv<<<192, 512, 0, stream>>>(Xh, Wqkv, Qb, Kb, Vb);
  transpose_v<<<dim3(32, 2, 8), 256, 0, stream>>>(Vb, Vtb);
  attn_kernel<<<512, 256, 0, stream>>>(Qb, Kb, Vtb, Ob);
  gemm8<4><<<256, 512, 0, stream>>>(Ob, Woh, 2048, out, bo);
}

// Round 9
// 203.791 us; speedup vs baseline: 1.4435x; 1.0444x over previous
//
#include <hip/hip_runtime.h>

typedef _Float16 f16;
typedef __attribute__((ext_vector_type(4))) _Float16 f16x4;
typedef __attribute__((ext_vector_type(8))) _Float16 f16x8;
typedef __attribute__((ext_vector_type(4))) float f32x4;

#define NB 2
#define NS 2048
#define NHID 2048
#define N_H 16
#define N_KV 4
#define N_HD 128

__device__ __forceinline__ void gload16(void* lds, const void* g) {
  __builtin_amdgcn_global_load_lds(
      (const __attribute__((address_space(1))) unsigned int*)g,
      (__attribute__((address_space(3))) unsigned int*)lds, 16, 0, 0);
}

// ---------------- fused f32 -> f16 convert for all 5 inputs ----------------
__global__ __launch_bounds__(256) void cvt_all(
    const float* __restrict__ hs, const float* __restrict__ Wq,
    const float* __restrict__ Wk, const float* __restrict__ Wv,
    const float* __restrict__ Wo, f16* __restrict__ Xh,
    f16* __restrict__ Wqkv, f16* __restrict__ Woh) {
  int i = blockIdx.x * 256 + threadIdx.x;  // float4 index, total 4718592
  const float* src;
  f16* dst;
  int j;
  if (i < 2097152)      { src = hs; dst = Xh;             j = i; }
  else if (i < 3145728) { src = Wq; dst = Wqkv;           j = i - 2097152; }
  else if (i < 3407872) { src = Wk; dst = Wqkv + 4194304; j = i - 3145728; }
  else if (i < 3670016) { src = Wv; dst = Wqkv + 5242880; j = i - 3407872; }
  else                  { src = Wo; dst = Woh;            j = i - 3670016; }
  const float4 v = reinterpret_cast<const float4*>(src)[j];
  f16x4 o = {(f16)v.x, (f16)v.y, (f16)v.z, (f16)v.w};
  reinterpret_cast<f16x4*>(dst)[j] = o;
}

// ---------------- QKV GEMM: 256x192 x BK=64, grid 256 = 1/CU, 4-phase ----------------
// 8 waves (2M x 4N; wave 128x48). 2 LDS buffers 56KB each. Per tile: 7 uniform
// 8KB granules (B=3, A=4). During tile T: q0/q1 stage A(T+1) (opposite buffer),
// q2/q3 stage B(T+2) (same buffer B-region; tile-T B reads drained at q0's
// closing barrier). SYNC DISCIPLINE: counted vmcnt at END of each tile's last
// phase, BEFORE its closing barrier -> every wave drains its loads for tile
// T+1 before the rendezvous that tile T+1's ds_reads follow (cross-wave safe).
// V written transposed directly.
__global__ __launch_bounds__(512, 2) void gemm_qkv(
    const f16* __restrict__ A, const f16* __restrict__ Bm,
    f16* __restrict__ q_out, f16* __restrict__ k_out, f16* __restrict__ vt_out) {
  constexpr int K = 2048;
  constexpr int NT = 32;
  __shared__ f16 lds[2][28672];
  const int t = threadIdx.x;
  const int l = t & 63, w = t >> 6;
  const int g = l >> 4, l15 = l & 15;
  const int wr = w >> 2, wc = w & 3;
  // XCD-rectangle swizzle over 16mb x 16nb
  const int orig = blockIdx.x;
  const int x = orig & 7, loc = orig >> 3;   // loc 0..31
  const int mb = (x & 3) * 4 + (loc & 3);
  const int nb = (x >> 2) * 8 + (loc >> 2);
  const f16* Ab = A + (size_t)(mb * 256) * K;
  const f16* Bb = Bm + (size_t)(nb * 192) * K;

  const int rr = ((t >> 5) << 3) | (t & 7);
  const int cc = (t >> 3) & 3;
  const int dstw = w * 512;
  // B granule j: dest f16 offset db = j*4096 + t*8 within the 12288-f16 B
  // region laid out as two 6144-f16 halves; invert the slot permutation.
  int srcB[3];
#pragma unroll
  for (int j = 0; j < 3; ++j) {
    int db0 = j * 4096 + t * 8;
    int h = (db0 >= 6144) ? 1 : 0;
    int u = (db0 - h * 6144) >> 3;
    int rowB = ((u >> 5) << 3) | (u & 7);
    int ccB = (u >> 3) & 3;
    srcB[j] = rowB * K + h * 32 + ccB * 8;
  }

  auto stageA = [&](int tile, int j) {  // j: h=j>>1, gi=j&1
    int h = j >> 1, gi = j & 1;
    gload16(&lds[tile & 1][h * 8192 + gi * 4096 + dstw],
            Ab + (size_t)(gi * 128 + rr) * K + tile * 64 + h * 32 + cc * 8);
  };
  auto stageB = [&](int tile, int j) {
    gload16(&lds[tile & 1][16384 + j * 4096 + dstw],
            Bb + (size_t)srcB[j] + tile * 64);
  };

  const int fragoff = ((l15 >> 3) << 8) + (g << 6) + ((l15 & 7) << 3);
  f32x4 acc[8][3] = {};

  // prologue: tile0 complete + tile1 B; drain all but tile1's 3 B, then barrier
#pragma unroll
  for (int j = 0; j < 3; ++j) stageB(0, j);
#pragma unroll
  for (int j = 0; j < 4; ++j) stageA(0, j);
#pragma unroll
  for (int j = 0; j < 3; ++j) stageB(1, j);
  asm volatile("s_waitcnt vmcnt(3)" ::: "memory");
  __builtin_amdgcn_s_barrier();

  f16x8 bf[3][2];
  for (int T = 0; T < NT; ++T) {
    const f16* buf = lds[T & 1];
#pragma unroll
    for (int q = 0; q < 4; ++q) {
      f16x8 af[2][2];
#pragma unroll
      for (int i = 0; i < 2; ++i)
#pragma unroll
        for (int ks = 0; ks < 2; ++ks)
          af[i][ks] = *reinterpret_cast<const f16x8*>(
              buf + ks * 8192 + (wr * 128 + (2 * q + i) * 16) * 32 + fragoff);
      if (q == 0) {
#pragma unroll
        for (int ni = 0; ni < 3; ++ni)
#pragma unroll
          for (int ks = 0; ks < 2; ++ks)
            bf[ni][ks] = *reinterpret_cast<const f16x8*>(
                buf + 16384 + ks * 6144 + (wc * 48 + ni * 16) * 32 + fragoff);
      }
      if (q == 0)      { if (T + 1 < NT) { stageA(T + 1, 0); stageA(T + 1, 1); } }
      else if (q == 1) { if (T + 1 < NT) { stageA(T + 1, 2); stageA(T + 1, 3); } }
      else if (q == 2) { if (T + 2 < NT) { stageB(T + 2, 0); stageB(T + 2, 1); } }
      else             { if (T + 2 < NT) { stageB(T + 2, 2); } }
      __builtin_amdgcn_s_barrier();
      asm volatile("s_waitcnt lgkmcnt(0)" ::: "memory");
      __builtin_amdgcn_sched_barrier(0);
      __builtin_amdgcn_s_setprio(1);
#pragma unroll
      for (int i = 0; i < 2; ++i)
#pragma unroll
        for (int ni = 0; ni < 3; ++ni)
#pragma unroll
          for (int ks = 0; ks < 2; ++ks)
            acc[2 * q + i][ni] = __builtin_amdgcn_mfma_f32_16x16x32_f16(
                af[i][ks], bf[ni][ks], acc[2 * q + i][ni], 0, 0, 0);
      __builtin_amdgcn_s_setprio(0);
      // end-of-tile: drain tile T+1's staged granules BEFORE the closing
      // barrier so next tile's ds_reads are cross-wave safe
      if (q == 3 && T + 1 < NT) {
        if (T + 2 < NT) asm volatile("s_waitcnt vmcnt(3)" ::: "memory");
        else            asm volatile("s_waitcnt vmcnt(0)" ::: "memory");
      }
      __builtin_amdgcn_s_barrier();
    }
  }

  // scatter epilogue; V written TRANSPOSED (f16x4 along s)
#pragma unroll
  for (int mi = 0; mi < 8; ++mi) {
    int m0 = mb * 256 + wr * 128 + mi * 16 + 4 * g;
    int b = m0 >> 11, s0 = m0 & (NS - 1);
#pragma unroll
    for (int ni = 0; ni < 3; ++ni) {
      int n = nb * 192 + wc * 48 + ni * 16 + l15;
      if (n < 2048) {
        int h = n >> 7, d = n & 127;
        f16* qp = q_out + (((size_t)(b * N_H + h)) * NS + s0) * N_HD + d;
#pragma unroll
        for (int r = 0; r < 4; ++r) qp[r * N_HD] = (f16)acc[mi][ni][r];
      } else if (n < 2560) {
        int n2 = n - 2048, kvh = n2 >> 7, d = n2 & 127;
        f16* kp = k_out + (((size_t)(b * N_KV + kvh)) * NS + s0) * N_HD + d;
#pragma unroll
        for (int r = 0; r < 4; ++r) kp[r * N_HD] = (f16)acc[mi][ni][r];
      } else {
        int n3 = n - 2560, kvh = n3 >> 7, d = n3 & 127;
        f16x4 o4 = {(f16)acc[mi][ni][0], (f16)acc[mi][ni][1],
                    (f16)acc[mi][ni][2], (f16)acc[mi][ni][3]};
        *reinterpret_cast<f16x4*>(
            vt_out + (((size_t)(b * N_KV + kvh)) * N_HD + d) * NS + s0) = o4;
      }
    }
  }
}

// ---------------- outproj GEMM: 128x256 x BK=64, grid 256 = 1/CU, 2-phase ----------------
// 8 waves (2M x 4N; wave 64x64). 2 LDS buffers 48KB. 6 granules/tile (A2,B4).
// q0 stages A(T+1) (opposite buffer); q1 stages B(T+2) (same buffer B-region,
// safe after q0's closing barrier). Counted vmcnt(4) at END of tile, before
// its closing barrier (cross-wave safe discipline).
__global__ __launch_bounds__(512, 2) void gemm_out(
    const f16* __restrict__ A, const f16* __restrict__ Bm,
    float* __restrict__ f_out, const float* __restrict__ bias) {
  constexpr int K = 2048;
  constexpr int NT = 32;
  __shared__ f16 lds[2][24576];
  const int t = threadIdx.x;
  const int l = t & 63, w = t >> 6;
  const int g = l >> 4, l15 = l & 15;
  const int wr = w >> 2, wc = w & 3;
  const int orig = blockIdx.x;
  const int x = orig & 7, loc = orig >> 3;   // loc 0..31
  const int mb = (x & 3) * 8 + (loc & 7);
  const int nb = (x >> 2) * 4 + (loc >> 3);
  const f16* Ab = A + (size_t)(mb * 128) * K;
  const f16* Bb = Bm + (size_t)(nb * 256) * K;

  const int rr = ((t >> 5) << 3) | (t & 7);
  const int cc = (t >> 3) & 3;
  const int dstw = w * 512;

  auto stageA = [&](int tile, int h) {
    gload16(&lds[tile & 1][h * 4096 + dstw],
            Ab + (size_t)rr * K + tile * 64 + h * 32 + cc * 8);
  };
  auto stageB = [&](int tile, int j) {  // j = h*2 + gi
    int h = j >> 1, gi = j & 1;
    gload16(&lds[tile & 1][8192 + h * 8192 + gi * 4096 + dstw],
            Bb + (size_t)(gi * 128 + rr) * K + tile * 64 + h * 32 + cc * 8);
  };

  const int fragoff = ((l15 >> 3) << 8) + (g << 6) + ((l15 & 7) << 3);
  f32x4 acc[4][4] = {};

  // prologue: tile0 all + tile1 B; drain all but tile1's 4 B, then barrier
  stageA(0, 0); stageA(0, 1);
#pragma unroll
  for (int j = 0; j < 4; ++j) stageB(0, j);
#pragma unroll
  for (int j = 0; j < 4; ++j) stageB(1, j);
  asm volatile("s_waitcnt vmcnt(4)" ::: "memory");
  __builtin_amdgcn_s_barrier();

  f16x8 bf[4][2];
  for (int T = 0; T < NT; ++T) {
    const f16* buf = lds[T & 1];
#pragma unroll
    for (int q = 0; q < 2; ++q) {
      f16x8 af[2][2];
#pragma unroll
      for (int i = 0; i < 2; ++i)
#pragma unroll
        for (int ks = 0; ks < 2; ++ks)
          af[i][ks] = *reinterpret_cast<const f16x8*>(
              buf + ks * 4096 + (wr * 64 + (2 * q + i) * 16) * 32 + fragoff);
      if (q == 0) {
#pragma unroll
        for (int ni = 0; ni < 4; ++ni)
#pragma unroll
          for (int ks = 0; ks < 2; ++ks)
            bf[ni][ks] = *reinterpret_cast<const f16x8*>(
                buf + 8192 + ks * 8192 + (wc * 64 + ni * 16) * 32 + fragoff);
      }
      if (q == 0) {
        if (T + 1 < NT) { stageA(T + 1, 0); stageA(T + 1, 1); }
      } else {
        if (T + 2 < NT) { stageB(T + 2, 0); stageB(T + 2, 1); stageB(T + 2, 2); stageB(T + 2, 3); }
      }
      __builtin_amdgcn_s_barrier();
      asm volatile("s_waitcnt lgkmcnt(0)" ::: "memory");
      __builtin_amdgcn_sched_barrier(0);
      __builtin_amdgcn_s_setprio(1);
#pragma unroll
      for (int i = 0; i < 2; ++i)
#pragma unroll
        for (int ni = 0; ni < 4; ++ni)
#pragma unroll
          for (int ks = 0; ks < 2; ++ks)
            acc[2 * q + i][ni] = __builtin_amdgcn_mfma_f32_16x16x32_f16(
                af[i][ks], bf[ni][ks], acc[2 * q + i][ni], 0, 0, 0);
      __builtin_amdgcn_s_setprio(0);
      if (q == 1 && T + 1 < NT) {
        if (T + 2 < NT) asm volatile("s_waitcnt vmcnt(4)" ::: "memory");
        else            asm volatile("s_waitcnt vmcnt(0)" ::: "memory");
      }
      __builtin_amdgcn_s_barrier();
    }
  }

#pragma unroll
  for (int mi = 0; mi < 4; ++mi) {
    int m0 = mb * 128 + wr * 64 + mi * 16 + 4 * g;
#pragma unroll
    for (int ni = 0; ni < 4; ++ni) {
      int n = nb * 256 + wc * 64 + ni * 16 + l15;
#pragma unroll
      for (int r = 0; r < 4; ++r)
        f_out[(size_t)(m0 + r) * NHID + n] = acc[mi][ni][r] + bias[n];
    }
  }
}

// ---------------- causal GQA flash attention (R5 structure, known-good) ----------------
__device__ __forceinline__ void stage_kv(const f16* __restrict__ Kp,
                                         const f16* __restrict__ Vp,
                                         f16* Kl, f16* Vl, int kt, int w, int l) {
#pragma unroll
  for (int it = 0; it < 4; ++it) {
    int cb = (it * 4 + w) * 64;
    int c = cb + l;
    int krow = c >> 4, pch = c & 15;
    int sch = (pch & 8) | ((pch ^ krow) & 7);
    gload16(Kl + cb * 8, Kp + (size_t)(kt * 64 + krow) * N_HD + sch * 8);
  }
#pragma unroll
  for (int it = 0; it < 4; ++it) {
    int cb = (it * 4 + w) * 64;
    int c = cb + l;
    int drow = c >> 3, pch = c & 7;
    int sch = (pch ^ drow) & 7;
    gload16(Vl + cb * 8, Vp + (size_t)drow * NS + kt * 64 + sch * 8);
  }
}

__device__ __forceinline__ void attn_step(
    const f16x8* qf, f32x4* oacc, float* mrow, float* lrow, int q0, int kt,
    const f16* Kl, const f16* Vl, f16* Pw, int g, int l15, bool diag) {
  // S = Q K^T (Q pre-scaled by log2e): acc D[q=4g+r][kpos=l15+16nt]
  f32x4 sacc[4];
#pragma unroll
  for (int nt = 0; nt < 4; ++nt) {
    f32x4 z = {0.f, 0.f, 0.f, 0.f};
#pragma unroll
    for (int ks = 0; ks < 4; ++ks) {
      int kr = nt * 16 + l15;
      int ch = ks * 4 + g;
      int sw = (ch & 8) | ((ch ^ kr) & 7);
      f16x8 kf = *reinterpret_cast<const f16x8*>(Kl + kr * 128 + sw * 8);
      z = __builtin_amdgcn_mfma_f32_16x16x32_f16(qf[ks], kf, z, 0, 0, 0);
    }
    sacc[nt] = z;
  }

  // causal mask + wave-parallel max; exp2; scale old state
  float p[4][4];
#pragma unroll
  for (int r = 0; r < 4; ++r) {
    int qg = q0 + r;
    float m = -3.0e38f;
#pragma unroll
    for (int nt = 0; nt < 4; ++nt) {
      float sv = sacc[nt][r];
      if (diag) {
        int kg = kt * 64 + nt * 16 + l15;
        if (kg > qg) sv = -3.0e38f;
      }
      p[nt][r] = sv;
      m = fmaxf(m, sv);
    }
#pragma unroll
    for (int off = 8; off >= 1; off >>= 1) m = fmaxf(m, __shfl_xor(m, off));
    float m2 = fmaxf(mrow[r], m);
    float alpha = __builtin_amdgcn_exp2f(mrow[r] - m2);
    mrow[r] = m2;
    lrow[r] *= alpha;
#pragma unroll
    for (int nt = 0; nt < 4; ++nt)
      p[nt][r] = __builtin_amdgcn_exp2f(p[nt][r] - m2);
#pragma unroll
    for (int dt = 0; dt < 8; ++dt) oacc[dt][r] *= alpha;
  }

  // P -> per-wave LDS (swizzled), then read back as A-op fragments
#pragma unroll
  for (int nt = 0; nt < 4; ++nt)
#pragma unroll
    for (int r = 0; r < 4; ++r) {
      int ql = 4 * g + r;
      int kp = nt * 16 + l15;
      int ch = kp >> 3;
      int idx = ql * 64 + (ch ^ (ql & 7)) * 8 + (kp & 7);
      Pw[idx] = (f16)p[nt][r];
    }
  asm volatile("s_waitcnt lgkmcnt(0)" ::: "memory");
  __builtin_amdgcn_sched_barrier(0);

  f16x8 pa[2];
#pragma unroll
  for (int ks2 = 0; ks2 < 2; ++ks2) {
    int ch = ks2 * 4 + g;
    pa[ks2] = *reinterpret_cast<const f16x8*>(&Pw[l15 * 64 + (ch ^ (l15 & 7)) * 8]);
  }
  // row-sum via ones-MFMA (all lanes get Sum_k P[row,k] in lacc[r])
  const f16x8 ones = {(f16)1.f, (f16)1.f, (f16)1.f, (f16)1.f,
                      (f16)1.f, (f16)1.f, (f16)1.f, (f16)1.f};
  f32x4 lacc = {0.f, 0.f, 0.f, 0.f};
#pragma unroll
  for (int ks2 = 0; ks2 < 2; ++ks2)
    lacc = __builtin_amdgcn_mfma_f32_16x16x32_f16(pa[ks2], ones, lacc, 0, 0, 0);
  // O += P V : B-op = V[k][d] from Vl[d][k]
#pragma unroll
  for (int dt = 0; dt < 8; ++dt)
#pragma unroll
    for (int ks2 = 0; ks2 < 2; ++ks2) {
      int d = dt * 16 + l15;
      int ch = ks2 * 4 + g;
      f16x8 vf = *reinterpret_cast<const f16x8*>(Vl + d * 64 + (ch ^ (d & 7)) * 8);
      oacc[dt] = __builtin_amdgcn_mfma_f32_16x16x32_f16(pa[ks2], vf, oacc[dt], 0, 0, 0);
    }
#pragma unroll
  for (int r = 0; r < 4; ++r) lrow[r] += lacc[r];
}

__global__ __launch_bounds__(256, 2) void attn_kernel(
    const f16* __restrict__ Q, const f16* __restrict__ K,
    const f16* __restrict__ Vt, f16* __restrict__ O) {
  __shared__ f16 Klds[2][64 * 128];
  __shared__ f16 Vlds[2][128 * 64];
  __shared__ f16 Plds[4][16 * 64];
  const int t = threadIdx.x, l = t & 63, w = t >> 6;
  const int g = l >> 4, l15 = l & 15;
  // XCD swizzle: XCD x owns (b,kvh) group so K/V stays L2-resident
  const int orig = blockIdx.x;               // 0..511
  const int x = orig & 7, loc = orig >> 3;   // loc 0..63
  const int b = x >> 2, kvh = x & 3;
  const int h = kvh * 4 + (loc & 3);
  const int pi = loc >> 2;                   // 0..15
  const int qtA = pi, qtB = 31 - pi;
  const f16* Qp = Q + ((size_t)(b * N_H + h)) * NS * N_HD;
  const f16* Kp = K + ((size_t)(b * N_KV + kvh)) * NS * N_HD;
  const f16* Vp = Vt + ((size_t)(b * N_KV + kvh)) * N_HD * NS;

  const f16 l2e = (f16)1.44269504f;
  f16x8 qfA[4], qfB[4];
  const int qrA = qtA * 64 + w * 16 + l15;
  const int qrB = qtB * 64 + w * 16 + l15;
#pragma unroll
  for (int ks = 0; ks < 4; ++ks) {
    qfA[ks] = *reinterpret_cast<const f16x8*>(Qp + (size_t)qrA * N_HD + ks * 32 + g * 8);
    qfB[ks] = *reinterpret_cast<const f16x8*>(Qp + (size_t)qrB * N_HD + ks * 32 + g * 8);
#pragma unroll
    for (int j = 0; j < 8; ++j) { qfA[ks][j] *= l2e; qfB[ks][j] *= l2e; }
  }

  f32x4 oA[8] = {}, oB[8] = {};
  float mA[4], lAr[4], mB[4], lBr[4];
#pragma unroll
  for (int r = 0; r < 4; ++r) {
    mA[r] = -3.0e38f; lAr[r] = 0.f;
    mB[r] = -3.0e38f; lBr[r] = 0.f;
  }
  const int q0A = qtA * 64 + w * 16 + 4 * g;
  const int q0B = qtB * 64 + w * 16 + 4 * g;

  const int nkt = qtB + 1;
  stage_kv(Kp, Vp, Klds[0], Vlds[0], 0, w, l);
  asm volatile("s_waitcnt vmcnt(0)" ::: "memory");
  __syncthreads();
  int cur = 0;
  for (int kt = 0; kt < nkt; ++kt) {
    if (kt + 1 < nkt)
      stage_kv(Kp, Vp, Klds[cur ^ 1], Vlds[cur ^ 1], kt + 1, w, l);
    attn_step(qfB, oB, mB, lBr, q0B, kt, Klds[cur], Vlds[cur], Plds[w], g, l15, kt == qtB);
    if (kt <= qtA)
      attn_step(qfA, oA, mA, lAr, q0A, kt, Klds[cur], Vlds[cur], Plds[w], g, l15, kt == qtA);
    asm volatile("s_waitcnt vmcnt(0)" ::: "memory");
    __syncthreads();
    cur ^= 1;
  }

  // normalize + write attn_out [B*S][NH*HD] fp16
#pragma unroll
  for (int r = 0; r < 4; ++r) {
    float invB = 1.0f / lBr[r];
    f16* orowB = O + (size_t)(b * NS + q0B + r) * NHID + h * N_HD;
#pragma unroll
    for (int dt = 0; dt < 8; ++dt) orowB[dt * 16 + l15] = (f16)(oB[dt][r] * invB);
    float invA = 1.0f / lAr[r];
    f16* orowA = O + (size_t)(b * NS + q0A + r) * NHID + h * N_HD;
#pragma unroll
    for (int dt = 0; dt < 8; ++dt) orowA[dt * 16 + l15] = (f16)(oA[dt][r] * invA);
  }
}

extern "C" void kernel_launch(void* const* d_in, const int* in_sizes, int n_in,
                              void* d_out, int out_size, void* d_ws, size_t ws_size,
                              hipStream_t stream) {
  const float* hs = (const float*)d_in[0];
  const float* Wq = (const float*)d_in[1];
  const float* Wk = (const float*)d_in[2];
  const float* Wv = (const float*)d_in[3];
  const float* Wo = (const float*)d_in[4];
  const float* bo = (const float*)d_in[5];
  float* out = (float*)d_out;

  char* ws = (char*)d_ws;
  f16* Xh   = (f16*)(ws);
  f16* Wqkv = (f16*)(ws + 16777216);
  f16* Woh  = (f16*)(ws + 29360128);
  f16* Qb   = (f16*)(ws + 37748736);
  f16* Kb   = (f16*)(ws + 54525952);
  f16* Vtb  = (f16*)(ws + 62914560);
  f16* Ob   = Xh;  // X dead after QKV GEMM; reuse for attention output

  cvt_all<<<18432, 256, 0, stream>>>(hs, Wq, Wk, Wv, Wo, Xh, Wqkv, Woh);
  gemm_qkv<<<256, 512, 0, stream>>>(Xh, Wqkv, Qb, Kb, Vtb);
  attn_kernel<<<512, 256, 0, stream>>>(Qb, Kb, Vtb, Ob);
  gemm_out<<<256, 512, 0, stream>>>(Ob, Woh, out, bo);
}